// Round 5
// baseline (17550.629 us; speedup 1.0000x reference)
//
#include <hip/hip_runtime.h>

#define B_ 128
#define T_ 200
#define INF_ 175
#define INFP_ 192
#define H_ 1024
#define G4_ 4096
#define OUTF_ 175
#define BH3_ (3 * B_ * H_)
#define NCELL 192
#define NDEC 22
#define NBLK (NCELL + NDEC)

typedef __bf16 bf16x8 __attribute__((ext_vector_type(8)));
typedef float f32x4 __attribute__((ext_vector_type(4)));

// ---- persistent device state ----
__device__ __attribute__((aligned(16))) __bf16 g_Wih1p[G4_ * INFP_];
__device__ __attribute__((aligned(16))) __bf16 g_Whh1[G4_ * H_];
__device__ __attribute__((aligned(16))) __bf16 g_Wih2[G4_ * H_];
__device__ __attribute__((aligned(16))) __bf16 g_Whh2[G4_ * H_];
__device__ __attribute__((aligned(16))) __bf16 g_Wih3[G4_ * H_];
__device__ __attribute__((aligned(16))) __bf16 g_Whh3[G4_ * H_];
__device__ __attribute__((aligned(16))) __bf16 g_Wdec[OUTF_ * H_];
__device__ float g_bsum[3 * G4_];
__device__ float g_bdec[OUTF_];
__device__ __attribute__((aligned(16))) __bf16 g_h[2][BH3_];
__device__ __attribute__((aligned(16))) __bf16 g_infp[B_ * INFP_];
__device__ int g_isf32;
__device__ int g_cnt;
__device__ int g_gen;
__device__ int g_dflag;

__device__ __forceinline__ f32x4 mfma_bf16(bf16x8 a, bf16x8 b, f32x4 c) {
    return __builtin_amdgcn_mfma_f32_16x16x32_bf16(a, b, c, 0, 0, 0);
}
__device__ __forceinline__ bf16x8 ld8(const __bf16* p) {
    return *reinterpret_cast<const bf16x8*>(p);
}
__device__ __forceinline__ float sigm(float x) { return 1.f / (1.f + expf(-x)); }
__device__ __forceinline__ float rdf(const void* p, long i, int f32) {
    return f32 ? ((const float*)p)[i] : (float)((const __bf16*)p)[i];
}

// bounded spin: normal wait is <5us; bound ~75ms converts any deadlock into a
// finite (garbage-result) failure instead of a dead container.
__device__ __forceinline__ void spinwait(int* addr, int target) {
    for (int it = 0; it < 300000; ++it) {
        if (__hip_atomic_load(addr, __ATOMIC_ACQUIRE, __HIP_MEMORY_SCOPE_AGENT) >= target)
            return;
        __builtin_amdgcn_s_sleep(8);
    }
}

// ---- dtype probe ----
__global__ void detect_k(const unsigned int* __restrict__ xw) {
    __shared__ int cnt;
    if (threadIdx.x == 0) cnt = 0;
    __syncthreads();
    unsigned int w = xw[threadIdx.x];
    int e = (w >> 7) & 0xFF;
    if (e >= 140) atomicAdd(&cnt, 1);
    __syncthreads();
    if (threadIdx.x == 0) g_isf32 = (cnt >= 16) ? 1 : 0;
}

// ---- prep: weights->bf16 globals, bias sums, zero state, infp(0), reset sync ----
__global__ void prep_k(const void* Wih1, const void* Whh1, const void* Wih2,
                       const void* Whh2, const void* Wih3, const void* Whh3,
                       const void* Wdec, const void* bih1, const void* bhh1,
                       const void* bih2, const void* bhh2, const void* bih3,
                       const void* bhh3, const void* bdec, const void* xseq) {
    const int f = g_isf32;
    const int idx = blockIdx.x * 256 + threadIdx.x;
    const int stride = gridDim.x * 256;
    if (idx == 0) { g_cnt = 0; g_gen = 0; g_dflag = 0; }
    for (int i = idx; i < G4_ * INFP_; i += stride) {
        int n = i / INFP_, k = i - n * INFP_;
        g_Wih1p[i] = (k < INF_) ? (__bf16)rdf(Wih1, (long)n * INF_ + k, f) : (__bf16)0.f;
    }
    for (int i = idx; i < G4_ * H_; i += stride) {
        g_Whh1[i] = (__bf16)rdf(Whh1, i, f);
        g_Wih2[i] = (__bf16)rdf(Wih2, i, f);
        g_Whh2[i] = (__bf16)rdf(Whh2, i, f);
        g_Wih3[i] = (__bf16)rdf(Wih3, i, f);
        g_Whh3[i] = (__bf16)rdf(Whh3, i, f);
    }
    for (int i = idx; i < OUTF_ * H_; i += stride) g_Wdec[i] = (__bf16)rdf(Wdec, i, f);
    for (int i = idx; i < G4_; i += stride) {
        g_bsum[i]           = rdf(bih1, i, f) + rdf(bhh1, i, f);
        g_bsum[G4_ + i]     = rdf(bih2, i, f) + rdf(bhh2, i, f);
        g_bsum[2 * G4_ + i] = rdf(bih3, i, f) + rdf(bhh3, i, f);
    }
    for (int i = idx; i < OUTF_; i += stride) g_bdec[i] = rdf(bdec, i, f);
    for (int i = idx; i < 2 * BH3_; i += stride) (&g_h[0][0])[i] = (__bf16)0.f;
    for (int i = idx; i < B_ * INFP_; i += stride) {
        int b = i / INFP_, k = i - b * INFP_;
        g_infp[i] = (k < INF_) ? (__bf16)rdf(xseq, (long)b * (T_ * INF_) + k, f) : (__bf16)0.f;
    }
}

// ---- grid barrier across NBLK=214 blocks (<=256 CUs, 1 blk/CU guaranteed) ----
__device__ __forceinline__ void gridbar(int target) {
    __syncthreads();
    if (threadIdx.x == 0) {
        __threadfence();
        int v = __hip_atomic_fetch_add(&g_cnt, 1, __ATOMIC_ACQ_REL, __HIP_MEMORY_SCOPE_AGENT);
        if (v == NBLK - 1) {
            __hip_atomic_store(&g_cnt, 0, __ATOMIC_RELAXED, __HIP_MEMORY_SCOPE_AGENT);
            __hip_atomic_store(&g_gen, target, __ATOMIC_RELEASE, __HIP_MEMORY_SCOPE_AGENT);
        } else {
            spinwait(&g_gen, target);
        }
    }
    __syncthreads();
}

struct CBun { bf16x8 a[4][2]; bf16x8 b[2][2]; };

// ---- persistent kernel: 200 timesteps, 1 grid barrier per step ----
__global__ __launch_bounds__(512, 2) void persist_k(const void* __restrict__ xseq,
                                                    void* __restrict__ dout) {
    __shared__ float s_acc[B_ * 4 * 16];  // 32KB: [row128][gate4][hc16]
    __shared__ float s_c[B_ * 16];        // 8KB:  [row128][hc16]
    const int bid = blockIdx.x;
    const int tid = threadIdx.x;
    const int lane = tid & 63;
    const int wid = tid >> 6;            // 0..7
    const int rlo = lane & 15, khi = lane >> 4;
    const int f32o = g_isf32;

    if (bid < NCELL) {
        // ================= CELL BLOCK =================
        const int L = bid >> 6;
        const int hc0 = (bid & 63) << 4;
        const int kk = wid >> 2;         // 0: x-operand, 1: recurrent operand
        const int mw = (wid >> 1) & 1;   // m-half
        const int nw = wid & 1;          // gate pair (0,1) vs (2,3)
        const float* bs = g_bsum + L * G4_;

        for (int i = tid; i < B_ * 16; i += 512) s_c[i] = 0.f;

        for (int p = 0; p < T_; ++p) {
            const __bf16* hin = g_h[p & 1];
            const __bf16* A; const __bf16* Bm; int sA, K;
            if (kk == 0) {
                if (L == 0) { A = g_infp; sA = INFP_; K = INFP_; Bm = g_Wih1p; }
                else {
                    A = hin + (L - 1) * B_ * H_; sA = H_; K = H_;
                    Bm = (L == 1) ? g_Wih2 : g_Wih3;
                }
            } else {
                A = hin + L * B_ * H_; sA = H_; K = H_;
                Bm = (L == 0) ? g_Whh1 : (L == 1) ? g_Whh2 : g_Whh3;
            }
            // L0 x-waves wait for this step's in_frame from dec blocks (lane0 spin,
            // wave-converged; acquire orders the wave's later infp loads)
            if (L == 0 && kk == 0 && p > 0) {
                if (lane == 0) spinwait(&g_dflag, NDEC * p);
            }

            const __bf16* Ab[4];
#pragma unroll
            for (int mf = 0; mf < 4; ++mf)
                Ab[mf] = A + (mw * 64 + mf * 16 + rlo) * sA + khi * 8;
            const __bf16* Bb[2];
#pragma unroll
            for (int nf = 0; nf < 2; ++nf)
                Bb[nf] = Bm + (long)((nw * 2 + nf) * H_ + hc0 + rlo) * K + khi * 8;

            const int nch = K >> 6;      // 3 (L0 x-op) or 16
            f32x4 acc[4][2] = {};

            auto loadc = [&](CBun& u, int i) {
                const int k = i << 6;
#pragma unroll
                for (int mf = 0; mf < 4; ++mf) {
                    u.a[mf][0] = ld8(Ab[mf] + k);
                    u.a[mf][1] = ld8(Ab[mf] + k + 32);
                }
#pragma unroll
                for (int nf = 0; nf < 2; ++nf) {
                    u.b[nf][0] = ld8(Bb[nf] + k);
                    u.b[nf][1] = ld8(Bb[nf] + k + 32);
                }
            };
            auto domfma = [&](CBun& u) {
#pragma unroll
                for (int kh = 0; kh < 2; ++kh)
#pragma unroll
                    for (int mf = 0; mf < 4; ++mf)
#pragma unroll
                        for (int nf = 0; nf < 2; ++nf)
                            acc[mf][nf] = mfma_bf16(u.a[mf][kh], u.b[nf][kh], acc[mf][nf]);
            };

            CBun u0, u1;
            loadc(u0, 0);
            if (nch > 1) loadc(u1, 1);
            for (int i = 0; i < nch; i += 2) {
                domfma(u0);
                if (i + 2 < nch) loadc(u0, i + 2);
                if (i + 1 < nch) {
                    domfma(u1);
                    if (i + 3 < nch) loadc(u1, i + 3);
                }
            }

            // K-split reduce through LDS
            if (kk == 1) {
#pragma unroll
                for (int mf = 0; mf < 4; ++mf)
#pragma unroll
                    for (int nf = 0; nf < 2; ++nf)
#pragma unroll
                        for (int j = 0; j < 4; ++j) {
                            int r = mw * 64 + mf * 16 + khi * 4 + j;
                            s_acc[(r * 4 + (nw * 2 + nf)) * 16 + rlo] = acc[mf][nf][j];
                        }
            }
            __syncthreads();
            if (kk == 0) {
#pragma unroll
                for (int mf = 0; mf < 4; ++mf)
#pragma unroll
                    for (int nf = 0; nf < 2; ++nf)
#pragma unroll
                        for (int j = 0; j < 4; ++j) {
                            int r = mw * 64 + mf * 16 + khi * 4 + j;
                            s_acc[(r * 4 + (nw * 2 + nf)) * 16 + rlo] += acc[mf][nf][j];
                        }
            }
            __syncthreads();

            // epilogue: all 8 waves, 16 rows each, 4 cols/lane
            {
                const int r = wid * 16 + rlo;
                const int hq = khi;
                f32x4 ga = *(const f32x4*)&s_acc[(r * 4 + 0) * 16 + hq * 4];
                f32x4 gf = *(const f32x4*)&s_acc[(r * 4 + 1) * 16 + hq * 4];
                f32x4 gg = *(const f32x4*)&s_acc[(r * 4 + 2) * 16 + hq * 4];
                f32x4 go = *(const f32x4*)&s_acc[(r * 4 + 3) * 16 + hq * 4];
                f32x4 cv = *(const f32x4*)&s_c[r * 16 + hq * 4];
                __bf16 hv[4];
#pragma unroll
                for (int e = 0; e < 4; ++e) {
                    int col = hc0 + hq * 4 + e;
                    float gi_ = ga[e] + bs[0 * H_ + col];
                    float gf_ = gf[e] + bs[1 * H_ + col];
                    float gg_ = gg[e] + bs[2 * H_ + col];
                    float go_ = go[e] + bs[3 * H_ + col];
                    float cn = sigm(gf_) * cv[e] + sigm(gi_) * tanhf(gg_);
                    cv[e] = cn;
                    hv[e] = (__bf16)(sigm(go_) * tanhf(cn));
                }
                *(f32x4*)&s_c[r * 16 + hq * 4] = cv;
                __bf16* hdst = g_h[(p + 1) & 1] + L * B_ * H_ + r * H_ + hc0 + hq * 4;
                *(uint2*)hdst = *(const uint2*)hv;
            }
            gridbar(p + 1);
        }
    } else {
        // ================= DEC BLOCK =================
        const int db = bid - NCELL;
        const int ntile = db % 11, mh = db / 11;
        const int kk = wid >> 2;         // K-split half
        const int mw = wid & 3;          // 4 m-frags of 16 rows
        const int col = ntile * 16 + rlo;
        const int colc = (col < OUTF_) ? col : (OUTF_ - 1);

        auto decwork = [&](int t, bool winf) {
            const __bf16* h2 = g_h[(t + 1) & 1] + 2 * B_ * H_;
            const __bf16* pa = h2 + (mh * 64 + mw * 16 + rlo) * H_ + kk * 512 + khi * 8;
            const __bf16* pb = g_Wdec + (long)colc * H_ + kk * 512 + khi * 8;
            f32x4 acc = {};
            bf16x8 a0, a1, b0, b1, c0, c1, d0, d1;
            a0 = ld8(pa); a1 = ld8(pa + 32); b0 = ld8(pb); b1 = ld8(pb + 32);
            c0 = ld8(pa + 64); c1 = ld8(pa + 96); d0 = ld8(pb + 64); d1 = ld8(pb + 96);
            for (int i = 0; i < 8; i += 2) {
                acc = mfma_bf16(a0, b0, acc);
                acc = mfma_bf16(a1, b1, acc);
                if (i + 2 < 8) {
                    int k = (i + 2) << 6;
                    a0 = ld8(pa + k); a1 = ld8(pa + k + 32);
                    b0 = ld8(pb + k); b1 = ld8(pb + k + 32);
                }
                acc = mfma_bf16(c0, d0, acc);
                acc = mfma_bf16(c1, d1, acc);
                if (i + 3 < 8) {
                    int k = (i + 3) << 6;
                    c0 = ld8(pa + k); c1 = ld8(pa + k + 32);
                    d0 = ld8(pb + k); d1 = ld8(pb + k + 32);
                }
            }
            if (kk == 1) {
#pragma unroll
                for (int j = 0; j < 4; ++j)
                    s_acc[(mw * 16 + khi * 4 + j) * 16 + rlo] = acc[j];
            }
            __syncthreads();
            if (kk == 0) {
#pragma unroll
                for (int j = 0; j < 4; ++j)
                    acc[j] += s_acc[(mw * 16 + khi * 4 + j) * 16 + rlo];
                if (col < OUTF_) {
                    const float bias = g_bdec[col];
                    const bool gt = (((t + 1) % 10) < 5);
#pragma unroll
                    for (int j = 0; j < 4; ++j) {
                        int row = mh * 64 + mw * 16 + khi * 4 + j;
                        float ov = acc[j] + bias;
                        long oidx = (long)row * (T_ * OUTF_) + (long)t * OUTF_ + col;
                        if (f32o) ((float*)dout)[oidx] = ov;
                        else ((__bf16*)dout)[oidx] = (__bf16)ov;
                        if (winf) {
                            float nxt = gt ? rdf(xseq, (long)row * (T_ * INF_) + (long)(t + 1) * INF_ + col, f32o)
                                           : ov;
                            g_infp[row * INFP_ + col] = (__bf16)nxt;
                        }
                    }
                }
            }
            __syncthreads();
            if (tid == 0) {
                __threadfence();
                __hip_atomic_fetch_add(&g_dflag, 1, __ATOMIC_RELEASE, __HIP_MEMORY_SCOPE_AGENT);
            }
        };

        for (int p = 0; p < T_; ++p) {
            if (p >= 1) decwork(p - 1, true);
            gridbar(p + 1);
        }
        decwork(T_ - 1, false);   // final output frame, no next in_frame
    }
}

extern "C" void kernel_launch(void* const* d_in, const int* in_sizes, int n_in,
                              void* d_out, int out_size, void* d_ws, size_t ws_size,
                              hipStream_t stream) {
    const void* xseq = d_in[0];
    detect_k<<<1, 256, 0, stream>>>((const unsigned int*)xseq);
    prep_k<<<2048, 256, 0, stream>>>(d_in[1], d_in[2], d_in[5], d_in[6], d_in[9],
                                     d_in[10], d_in[13], d_in[3], d_in[4], d_in[7],
                                     d_in[8], d_in[11], d_in[12], d_in[14], xseq);
    persist_k<<<NBLK, 512, 0, stream>>>(xseq, d_out);
}